// Round 12
// baseline (605.596 us; speedup 1.0000x reference)
//
#include <hip/hip_runtime.h>

typedef __attribute__((ext_vector_type(8))) short bf16x8;
typedef __attribute__((ext_vector_type(4))) float f32x4;

#define B_ROWS 262144
#define K_CODES 1024
#define DIM 64
// screen ambiguity threshold in s-units (s = dot - w2/2; d-gap = 2*s-gap).
// 8-bit packed-key noise (<=0.008 pairwise at |s|<=128) + bf16-split dot
// error (<=0.004 pairwise) -> 0.012; SDELTA=0.015 with margin.
#define SDELTA 0.015f
#define NREP 8

// output layout (floats)
#define OUT_ZQ 0
#define OUT_IDX 16777216
#define OUT_LOSS 17039360
#define OUT_NEWCS 17039361
#define OUT_NEWES 17040385
#define OUT_NEWW 17105921

// ws layout (float indices); ~10.9 MB total
#define WS_LOSS   0
#define WS_QCOUNT 1
#define WS_W2     16
#define WS_SMOOTH 1040
#define WS_WHIP   2064      // permuted hi codebook: 8192 granules x 16B
#define WS_WLOP   34832     // permuted lo codebook
#define WS_CPART  67600     // NREP x 1024 count replicas
#define WS_EPART  100368    // NREP x 65536 embed-sum replicas (global atomics)
#define WS_MINI   2197520   // int[262144]; bit31 = ambiguous
#define WS_QUEUE  2459664   // int[262144]

static __device__ __forceinline__ unsigned short f2bf(float x) {
    unsigned u = __float_as_uint(x);
    return (unsigned short)((u + 0x7fffu + ((u >> 16) & 1u)) >> 16);  // RN-even
}
static __device__ __forceinline__ float bf2f(unsigned short u) {
    return __uint_as_float(((unsigned)u) << 16);
}

// sum across each 16-lane group via DPP row_ror (VALU pipe only -- r8 lesson:
// __shfl_xor chains hit the LDS pipe, ~300cyc/code serial at low occupancy)
static __device__ __forceinline__ float red16(float x) {
    int v;
    v = __builtin_amdgcn_update_dpp(0, __float_as_int(x), 0x128, 0xF, 0xF, true);
    x += __int_as_float(v);
    v = __builtin_amdgcn_update_dpp(0, __float_as_int(x), 0x124, 0xF, 0xF, true);
    x += __int_as_float(v);
    v = __builtin_amdgcn_update_dpp(0, __float_as_int(x), 0x122, 0xF, 0xF, true);
    x += __int_as_float(v);
    v = __builtin_amdgcn_update_dpp(0, __float_as_int(x), 0x121, 0xF, 0xF, true);
    x += __int_as_float(v);
    return x;
}

static __device__ __forceinline__ void cvt_frag(const float* zrow, bf16x8& hi, bf16x8& lo) {
    float4 f0 = *(const float4*)zrow;
    float4 f1 = *(const float4*)(zrow + 4);
    float tf[8] = {f0.x, f0.y, f0.z, f0.w, f1.x, f1.y, f1.z, f1.w};
#pragma unroll
    for (int j = 0; j < 8; ++j) {
        unsigned short h = f2bf(tf[j]);
        hi[j] = (short)h;
        lo[j] = (short)f2bf(tf[j] - bf2f(h));
    }
}

// blocks 0..3: w2 row norms. blocks 4..35: permute codebook into MFMA-granule
// order: chunk c (128 codes), position p: granule = (code c*128+(p>>7)*16+(p&15),
// octet ((p>>6)&1)*4 + ((p>>4)&3)). Lane l reads granule base+l -> 16 codes x
// one K=32 half; base+l+64 -> same codes, other K half.
__global__ __launch_bounds__(256) void vq_prep(const float* __restrict__ w,
                                               float* __restrict__ ws) {
    int b = blockIdx.x, tid = threadIdx.x;
    if (b < 4) {
        int k = b * 256 + tid;
        const float4* w4 = (const float4*)(w + (size_t)k * DIM);
        float s = 0.f;
#pragma unroll
        for (int j = 0; j < 16; ++j) {
            float4 v = w4[j];
            s += v.x * v.x + v.y * v.y + v.z * v.z + v.w * v.w;
        }
        ws[WS_W2 + k] = s;
    } else {
        int i = (b - 4) * 256 + tid;  // granule index 0..8191
        int p = i & 1023, c = i >> 10;
        int code = c * 128 + ((p >> 7) << 4) + (p & 15);
        int octet = ((p >> 6) & 1) * 4 + ((p >> 4) & 3);
        const float* src = w + (size_t)code * DIM + octet * 8;
        float4 f0 = *(const float4*)src;
        float4 f1 = *(const float4*)(src + 4);
        float tf[8] = {f0.x, f0.y, f0.z, f0.w, f1.x, f1.y, f1.z, f1.w};
        bf16x8 hv, lv;
#pragma unroll
        for (int j = 0; j < 8; ++j) {
            unsigned short hb = f2bf(tf[j]);
            hv[j] = (short)hb;
            lv[j] = (short)f2bf(tf[j] - bf2f(hb));
        }
        ((bf16x8*)(ws + WS_WHIP))[i] = hv;
        ((bf16x8*)(ws + WS_WLOP))[i] = lv;
    }
}

// MFMA 16x16x32 screening, barrier-free, operand-swapped (A=codebook, B=z).
// Each lane's 4 acc values are 4 codes of ONE z-row; w2/2 pre-folded into
// the MFMA C-init. 8-BIT packed keys: lane-local candidate index
// (cch*32+tg*4+r, q implicit) in the low 8 mantissa bits. Full code
// recovered in the epilogue with an exact (val,idx) take-reduce across the
// 4 q-lanes. Corrupted orderings have gap <= SDELTA -> exact fixup path.
__global__ __launch_bounds__(256)
__attribute__((amdgpu_waves_per_eu(3, 4))) void vq_screen_kernel(
    const float* __restrict__ z, float* __restrict__ ws) {
    __shared__ float lds_w2h[K_CODES];  // -w2/2

    int tid = threadIdx.x;
    int l = tid & 63, wave = tid >> 6;
    int m = l & 15, q = l >> 4;

    {
        float4 wv = ((const float4*)(ws + WS_W2))[tid];
        float4 hv;
        hv.x = -0.5f * wv.x;
        hv.y = -0.5f * wv.y;
        hv.z = -0.5f * wv.z;
        hv.w = -0.5f * wv.w;
        *(float4*)&lds_w2h[tid * 4] = hv;
    }

    int rowbase = blockIdx.x * 128 + wave * 32;
    bf16x8 zhi[2][2], zlo[2][2];
#pragma unroll
    for (int g = 0; g < 2; ++g) {
        const float* zr = z + (size_t)(rowbase + g * 16 + m) * DIM + q * 8;
        cvt_frag(zr, zhi[g][0], zlo[g][0]);
        cvt_frag(zr + 32, zhi[g][1], zlo[g][1]);
    }

    float kv[2], k2[2];
    kv[0] = kv[1] = -3.4e38f;
    k2[0] = k2[1] = -3.4e38f;

    const bf16x8* __restrict__ gh = (const bf16x8*)(ws + WS_WHIP);
    const bf16x8* __restrict__ gl = (const bf16x8*)(ws + WS_WLOP);

    __syncthreads();  // w2h staged; the only barrier in the kernel

    for (int cch = 0; cch < 8; ++cch) {
#pragma unroll 2
        for (int tg = 0; tg < 8; ++tg) {
            int gi = cch * 1024 + tg * 128 + l;
            bf16x8 bh0 = gh[gi];        // codes cbase16, K 0..31 (hi)
            bf16x8 bh1 = gh[gi + 64];   // same codes, K 32..63 (hi)
            bf16x8 bl0 = gl[gi];
            bf16x8 bl1 = gl[gi + 64];
            unsigned cbase = (unsigned)(cch * 128 + tg * 16 + q * 4);
            unsigned ibase = (unsigned)((cch * 8 + tg) * 4);  // 8-bit local idx
            f32x4 cinit = *(const f32x4*)&lds_w2h[cbase];  // -w2/2 for 4 codes
#pragma unroll
            for (int g = 0; g < 2; ++g) {
                f32x4 acc = cinit;
                acc = __builtin_amdgcn_mfma_f32_16x16x32_bf16(bh0, zlo[g][0], acc, 0, 0, 0);
                acc = __builtin_amdgcn_mfma_f32_16x16x32_bf16(bl0, zhi[g][0], acc, 0, 0, 0);
                acc = __builtin_amdgcn_mfma_f32_16x16x32_bf16(bh1, zlo[g][1], acc, 0, 0, 0);
                acc = __builtin_amdgcn_mfma_f32_16x16x32_bf16(bl1, zhi[g][1], acc, 0, 0, 0);
                acc = __builtin_amdgcn_mfma_f32_16x16x32_bf16(bh0, zhi[g][0], acc, 0, 0, 0);
                acc = __builtin_amdgcn_mfma_f32_16x16x32_bf16(bh1, zhi[g][1], acc, 0, 0, 0);
                // pack local idx into low 8 mantissa bits (v_and_or_b32 each)
                float a0 = __uint_as_float((__float_as_uint(acc[0]) & 0xFFFFFF00u) | ibase);
                float a1 = __uint_as_float((__float_as_uint(acc[1]) & 0xFFFFFF00u) | (ibase + 1u));
                float a2 = __uint_as_float((__float_as_uint(acc[2]) & 0xFFFFFF00u) | (ibase + 2u));
                float a3 = __uint_as_float((__float_as_uint(acc[3]) & 0xFFFFFF00u) | (ibase + 3u));
                // top-2 of 4 (tournament), then merge into running top-2
                float m01 = fmaxf(a0, a1), n01 = fminf(a0, a1);
                float m23 = fmaxf(a2, a3), n23 = fminf(a2, a3);
                float top = fmaxf(m01, m23);
                float sec = fmaxf(fmaxf(fminf(m01, m23), n01), n23);  // max3
                k2[g] = fmaxf(fmaxf(k2[g], sec), fminf(kv[g], top));  // max3
                kv[g] = fmaxf(kv[g], top);
            }
        }
    }

    // unpack (masked value, full code), exact take-reduce across the 4 q-lanes
    float mv[2], m2[2];
    int mi[2];
#pragma unroll
    for (int g = 0; g < 2; ++g) {
        unsigned kb = __float_as_uint(kv[g]);
        unsigned i8 = kb & 255u;
        mi[g] = (int)((i8 >> 5) * 128 + ((i8 >> 2) & 7) * 16 + (unsigned)q * 4 + (i8 & 3));
        mv[g] = __uint_as_float(kb & 0xFFFFFF00u);
        m2[g] = __uint_as_float(__float_as_uint(k2[g]) & 0xFFFFFF00u);
    }
#pragma unroll
    for (int o = 16; o < 64; o <<= 1) {
#pragma unroll
        for (int g = 0; g < 2; ++g) {
            float ov = __shfl_xor(mv[g], o, 64);
            float ov2 = __shfl_xor(m2[g], o, 64);
            int oi = __shfl_xor(mi[g], o, 64);
            float nm2 = fmaxf(fmaxf(m2[g], ov2), fminf(mv[g], ov));
            bool take = (ov > mv[g]) || (ov == mv[g] && oi < mi[g]);
            mv[g] = take ? ov : mv[g];
            mi[g] = take ? oi : mi[g];
            m2[g] = nm2;
        }
    }
    if (q == 0) {
#pragma unroll
        for (int g = 0; g < 2; ++g) {
            bool amb = (mv[g] - m2[g]) <= SDELTA;
            ((int*)ws)[WS_MINI + rowbase + g * 16 + m] = mi[g] | (amb ? 0x80000000 : 0);
        }
    }
}

// Per-row: unambiguous -> write idx, z_q_st, loss; ambiguous -> enqueue.
// Wave-cooperative: 16 lanes per row (float4 per lane), 4 rows per step;
// every z load / w load / z_q store is a contiguous, coalesced 1KB/instr.
__global__ __launch_bounds__(256) void vq_gather_kernel(
    const float* __restrict__ z, const float* __restrict__ w,
    float* __restrict__ ws, float* __restrict__ out) {
    __shared__ float lred[4];
    int tid = threadIdx.x;
    int lane = tid & 63, wave = tid >> 6;
    int rsub = lane >> 4;  // 0..3: which of 4 rows this lane serves
    int d4 = lane & 15;    // float4 index within the 64-float row
    int wavebase = blockIdx.x * 256 + wave * 64;

    // prefetch all 16 enc values (independent scalar loads -> MLP)
    int encv[16];
#pragma unroll
    for (int s = 0; s < 16; ++s)
        encv[s] = ((const int*)ws)[WS_MINI + wavebase + s * 4 + rsub];

    float lsum = 0.f;
#pragma unroll
    for (int s = 0; s < 16; ++s) {
        int row = wavebase + s * 4 + rsub;
        int enc = encv[s];
        if (enc >= 0) {
            float4 x = ((const float4*)(z + (size_t)row * DIM))[d4];
            float4 qv = ((const float4*)(w + (size_t)enc * DIM))[d4];
            float4 st;
            st.x = x.x + (qv.x - x.x);
            st.y = x.y + (qv.y - x.y);
            st.z = x.z + (qv.z - x.z);
            st.w = x.w + (qv.w - x.w);
            ((float4*)(out + OUT_ZQ + (size_t)row * DIM))[d4] = st;
            float e0 = x.x - qv.x, e1 = x.y - qv.y, e2 = x.z - qv.z, e3 = x.w - qv.w;
            lsum += e0 * e0;
            lsum += e1 * e1;
            lsum += e2 * e2;
            lsum += e3 * e3;
            if (d4 == 0) out[OUT_IDX + row] = (float)enc;
        } else if (d4 == 0) {
            int pos = atomicAdd((int*)ws + WS_QCOUNT, 1);
            ((int*)ws)[WS_QUEUE + pos] = row;
        }
    }
#pragma unroll
    for (int o = 32; o; o >>= 1) lsum += __shfl_down(lsum, o, 64);
    if (lane == 0) lred[wave] = lsum;
    __syncthreads();
    if (tid == 0) atomicAdd(ws + WS_LOSS, lred[0] + lred[1] + lred[2] + lred[3]);
}

// Exact fp32 argmin for ambiguous rows. Block = 4 rows x 4 waves; each wave
// scans a disjoint 256-code quarter for the SAME 4 rows (w reads broadcast
// across the 4 row-groups in-wave; 16-lane dot reduce via DPP row_ror).
// LDS-combine keeps the exact lowest-index tie-break.
__global__ __launch_bounds__(256) void vq_fixup_kernel(
    const float* __restrict__ z, const float* __restrict__ w,
    float* __restrict__ ws, float* __restrict__ out) {
    const float* __restrict__ w2 = ws + WS_W2;
    __shared__ float sdd[4][4];
    __shared__ int sbi[4][4];
    int count = ((const int*)ws)[WS_QCOUNT];
    int tid = threadIdx.x;
    int lane = tid & 63, wave = tid >> 6;
    int sub = lane >> 4, d4 = lane & 15;
    float lacc = 0.f;
    for (int q0 = blockIdx.x * 4; q0 < count; q0 += gridDim.x * 4) {
        int qi = q0 + sub;
        bool active = qi < count;
        int row = ((const int*)ws)[WS_QUEUE + (active ? qi : 0)];
        float4 zx = ((const float4*)(z + (size_t)row * DIM))[d4];
        float zp = zx.x * zx.x;
        zp = fmaf(zx.y, zx.y, zp);
        zp = fmaf(zx.z, zx.z, zp);
        zp = fmaf(zx.w, zx.w, zp);
        float z2 = red16(zp);
        float best = 3.4e38f;
        int bi = 0;
        int c0 = wave * 256;
#pragma unroll 4
        for (int cc = 0; cc < 256; ++cc) {
            int c = c0 + cc;
            float4 wv4 = ((const float4*)(w + (size_t)c * DIM))[d4];
            float p = zx.x * wv4.x;
            p = fmaf(zx.y, wv4.y, p);
            p = fmaf(zx.z, wv4.z, p);
            p = fmaf(zx.w, wv4.w, p);
            p = red16(p);
            float dd = (z2 - 2.f * p) + w2[c];
            if (dd < best) { best = dd; bi = c; }
        }
        if (d4 == 0) { sdd[wave][sub] = best; sbi[wave][sub] = bi; }
        __syncthreads();
        if (wave == 0 && active) {
            float fb = sdd[0][sub];
            int fbi = sbi[0][sub];
#pragma unroll
            for (int v = 1; v < 4; ++v) {
                float od = sdd[v][sub];
                int oi = sbi[v][sub];
                if (od < fb || (od == fb && oi < fbi)) { fb = od; fbi = oi; }
            }
            float4 qv = ((const float4*)(w + (size_t)fbi * DIM))[d4];
            float4 st;
            st.x = zx.x + (qv.x - zx.x);
            st.y = zx.y + (qv.y - zx.y);
            st.z = zx.z + (qv.z - zx.z);
            st.w = zx.w + (qv.w - zx.w);
            ((float4*)(out + OUT_ZQ + (size_t)row * DIM))[d4] = st;
            float e0 = zx.x - qv.x, e1 = zx.y - qv.y;
            float e2 = zx.z - qv.z, e3 = zx.w - qv.w;
            float ls = e0 * e0 + e1 * e1 + e2 * e2 + e3 * e3;
            ls = red16(ls);
            if (d4 == 0) {
                out[OUT_IDX + row] = (float)fbi;
                lacc += ls;
            }
        }
        __syncthreads();
    }
    lacc += __shfl_xor(lacc, 16, 64);
    lacc += __shfl_xor(lacc, 32, 64);
    if (tid == 0 && lacc != 0.f) atomicAdd(ws + WS_LOSS, lacc);
}

// Segment-sum via FULL-LINE streaming + replicated global atomics.
// r10/r11 lesson: every LDS-accumulator layout is walled at ~400 GB/s of
// L2-miss traffic (dim-split forces 64B quarter-line reads; code-split
// forces random row gathers) -- duration invariant to codegen/MLP. Only
// full-line sequential float4 reads reach streaming BW. So: wave = 4
// consecutive rows x 16 lanes x float4 (the gather kernel's proven coalesced
// pattern, but sequential), one clean 64MB z pass; the data-dependent
// scatter goes to 8 REPLICATED global accumulators (EPART, L2-resident,
// 256KB each; replica = blockIdx&7) via device-scope atomicAdd. Counts into
// 8 CPART replicas. Replicas zeroed by hipMemsetAsync up front.
__global__ __launch_bounds__(256) void vq_embed_kernel(
    const float* __restrict__ z, const float* __restrict__ idx_f,
    float* __restrict__ ws) {
    int tid = threadIdx.x;
    int lane = tid & 63, wave = tid >> 6;
    int sub = lane >> 4, d4 = lane & 15;
    int rep = blockIdx.x & (NREP - 1);
    float* __restrict__ eacc = ws + WS_EPART + rep * (K_CODES * DIM);
    float* __restrict__ cacc = ws + WS_CPART + rep * K_CODES;
    int base = blockIdx.x * 128 + wave * 4 + sub;  // 8 steps x 16 rows/block
#pragma unroll 2
    for (int it = 0; it < 8; ++it) {
        int row = base + it * 16;
        float cf = idx_f[row];
        float4 zv = ((const float4*)(z + (size_t)row * DIM))[d4];
        int code = (int)cf;
        float* dst = eacc + code * DIM + d4 * 4;
        atomicAdd(dst + 0, zv.x);
        atomicAdd(dst + 1, zv.y);
        atomicAdd(dst + 2, zv.z);
        atomicAdd(dst + 3, zv.w);
        if (d4 == 0) atomicAdd(cacc + code, 1.f);
    }
}

__global__ __launch_bounds__(1024) void vq_finalize1_kernel(
    const float* __restrict__ ema_cs, float* __restrict__ ws,
    float* __restrict__ out) {
    int k = threadIdx.x;
    float c = 0.f;
#pragma unroll
    for (int r = 0; r < NREP; ++r) c += ws[WS_CPART + r * K_CODES + k];
    float nc = 0.99f * ema_cs[k] + 0.01f * c;
    out[OUT_NEWCS + k] = nc;

    float s = nc;
#pragma unroll
    for (int o = 32; o; o >>= 1) s += __shfl_down(s, o, 64);
    __shared__ float red[16];
    __shared__ float n_sh;
    if ((k & 63) == 0) red[k >> 6] = s;
    __syncthreads();
    if (k == 0) {
        float n = 0.f;
#pragma unroll
        for (int i = 0; i < 16; ++i) n += red[i];
        n_sh = n;
        out[OUT_LOSS] = 0.25f * (ws[WS_LOSS] / 16777216.0f);
    }
    __syncthreads();
    float n = n_sh;
    ws[WS_SMOOTH + k] = (nc + 1e-5f) / (n + 0.01024f) * n;
}

__global__ __launch_bounds__(256) void vq_finalize2_kernel(
    const float* __restrict__ ema_es, const float* __restrict__ ws,
    float* __restrict__ out) {
    int i = blockIdx.x * 256 + threadIdx.x;  // 65536 elems = code*64+dim
    int code = i >> 6;
    float e = 0.f;
#pragma unroll
    for (int r = 0; r < NREP; ++r) e += ws[WS_EPART + r * (K_CODES * DIM) + i];
    float es = 0.99f * ema_es[i] + 0.01f * e;
    out[OUT_NEWES + i] = es;
    out[OUT_NEWW + i] = es / ws[WS_SMOOTH + code];
}

extern "C" void kernel_launch(void* const* d_in, const int* in_sizes, int n_in,
                              void* d_out, int out_size, void* d_ws, size_t ws_size,
                              hipStream_t stream) {
    const float* z = (const float*)d_in[0];
    const float* weight = (const float*)d_in[1];
    const float* ema_cs = (const float*)d_in[2];
    const float* ema_es = (const float*)d_in[3];
    float* out = (float*)d_out;
    float* ws = (float*)d_ws;

    hipMemsetAsync(ws, 0, 64, stream);  // loss + queue counter
    hipMemsetAsync(ws + WS_CPART, 0, NREP * K_CODES * 4, stream);
    hipMemsetAsync(ws + WS_EPART, 0, NREP * K_CODES * DIM * 4, stream);
    vq_prep<<<36, 256, 0, stream>>>(weight, ws);
    vq_screen_kernel<<<B_ROWS / 128, 256, 0, stream>>>(z, ws);
    vq_gather_kernel<<<B_ROWS / 256, 256, 0, stream>>>(z, weight, ws, out);
    vq_fixup_kernel<<<512, 256, 0, stream>>>(z, weight, ws, out);
    vq_embed_kernel<<<B_ROWS / 128, 256, 0, stream>>>(z, out + OUT_IDX, ws);
    vq_finalize1_kernel<<<1, 1024, 0, stream>>>(ema_cs, ws, out);
    vq_finalize2_kernel<<<256, 256, 0, stream>>>(ema_es, ws, out);
}

// Round 13
// 423.019 us; speedup vs baseline: 1.4316x; 1.4316x over previous
//
#include <hip/hip_runtime.h>

typedef __attribute__((ext_vector_type(8))) short bf16x8;
typedef __attribute__((ext_vector_type(4))) float f32x4;

#define B_ROWS 262144
#define K_CODES 1024
#define DIM 64
// screen ambiguity threshold in s-units (s = dot - w2/2; d-gap = 2*s-gap).
// 8-bit packed-key noise (<=0.008 pairwise at |s|<=128) + bf16-split dot
// error (<=0.004 pairwise) -> 0.012; SDELTA=0.015 with margin.
#define SDELTA 0.015f

// output layout (floats)
#define OUT_ZQ 0
#define OUT_IDX 16777216
#define OUT_LOSS 17039360
#define OUT_NEWCS 17039361
#define OUT_NEWES 17040385
#define OUT_NEWW 17105921

// ws layout (float indices); ~10.9 MB total
#define WS_LOSS   0
#define WS_QCOUNT 1
#define WS_W2     16
#define WS_SMOOTH 1040
#define WS_WHIP   2064      // permuted hi codebook: 8192 granules x 16B
#define WS_WLOP   34832     // permuted lo codebook
#define WS_CPART  67600     // 512 blocks * 64 codes  (exactly 32768)
#define WS_EPART  100368    // 512 blocks * 64 codes * 64 dims (exactly 2097152)
#define WS_MINI   2197520   // int[262144]; bit31 = ambiguous
#define WS_QUEUE  2459664   // int[262144]

static __device__ __forceinline__ unsigned short f2bf(float x) {
    unsigned u = __float_as_uint(x);
    return (unsigned short)((u + 0x7fffu + ((u >> 16) & 1u)) >> 16);  // RN-even
}
static __device__ __forceinline__ float bf2f(unsigned short u) {
    return __uint_as_float(((unsigned)u) << 16);
}

// sum across each 16-lane group via DPP row_ror (VALU pipe only -- r8 lesson:
// __shfl_xor chains hit the LDS pipe, ~300cyc/code serial at low occupancy)
static __device__ __forceinline__ float red16(float x) {
    int v;
    v = __builtin_amdgcn_update_dpp(0, __float_as_int(x), 0x128, 0xF, 0xF, true);
    x += __int_as_float(v);
    v = __builtin_amdgcn_update_dpp(0, __float_as_int(x), 0x124, 0xF, 0xF, true);
    x += __int_as_float(v);
    v = __builtin_amdgcn_update_dpp(0, __float_as_int(x), 0x122, 0xF, 0xF, true);
    x += __int_as_float(v);
    v = __builtin_amdgcn_update_dpp(0, __float_as_int(x), 0x121, 0xF, 0xF, true);
    x += __int_as_float(v);
    return x;
}

static __device__ __forceinline__ void cvt_frag(const float* zrow, bf16x8& hi, bf16x8& lo) {
    float4 f0 = *(const float4*)zrow;
    float4 f1 = *(const float4*)(zrow + 4);
    float tf[8] = {f0.x, f0.y, f0.z, f0.w, f1.x, f1.y, f1.z, f1.w};
#pragma unroll
    for (int j = 0; j < 8; ++j) {
        unsigned short h = f2bf(tf[j]);
        hi[j] = (short)h;
        lo[j] = (short)f2bf(tf[j] - bf2f(h));
    }
}

// blocks 0..3: w2 row norms. blocks 4..35: permute codebook into MFMA-granule
// order: chunk c (128 codes), position p: granule = (code c*128+(p>>7)*16+(p&15),
// octet ((p>>6)&1)*4 + ((p>>4)&3)). Lane l reads granule base+l -> 16 codes x
// one K=32 half; base+l+64 -> same codes, other K half.
__global__ __launch_bounds__(256) void vq_prep(const float* __restrict__ w,
                                               float* __restrict__ ws) {
    int b = blockIdx.x, tid = threadIdx.x;
    if (b < 4) {
        int k = b * 256 + tid;
        const float4* w4 = (const float4*)(w + (size_t)k * DIM);
        float s = 0.f;
#pragma unroll
        for (int j = 0; j < 16; ++j) {
            float4 v = w4[j];
            s += v.x * v.x + v.y * v.y + v.z * v.z + v.w * v.w;
        }
        ws[WS_W2 + k] = s;
    } else {
        int i = (b - 4) * 256 + tid;  // granule index 0..8191
        int p = i & 1023, c = i >> 10;
        int code = c * 128 + ((p >> 7) << 4) + (p & 15);
        int octet = ((p >> 6) & 1) * 4 + ((p >> 4) & 3);
        const float* src = w + (size_t)code * DIM + octet * 8;
        float4 f0 = *(const float4*)src;
        float4 f1 = *(const float4*)(src + 4);
        float tf[8] = {f0.x, f0.y, f0.z, f0.w, f1.x, f1.y, f1.z, f1.w};
        bf16x8 hv, lv;
#pragma unroll
        for (int j = 0; j < 8; ++j) {
            unsigned short hb = f2bf(tf[j]);
            hv[j] = (short)hb;
            lv[j] = (short)f2bf(tf[j] - bf2f(hb));
        }
        ((bf16x8*)(ws + WS_WHIP))[i] = hv;
        ((bf16x8*)(ws + WS_WLOP))[i] = lv;
    }
}

// MFMA 16x16x32 screening, barrier-free, operand-swapped (A=codebook, B=z).
// Each lane's 4 acc values are 4 codes of ONE z-row; w2/2 pre-folded into
// the MFMA C-init. 8-BIT packed keys: lane-local candidate index
// (cch*32+tg*4+r, q implicit) in the low 8 mantissa bits. Full code
// recovered in the epilogue with an exact (val,idx) take-reduce across the
// 4 q-lanes. Corrupted orderings have gap <= SDELTA -> exact fixup path.
__global__ __launch_bounds__(256)
__attribute__((amdgpu_waves_per_eu(3, 4))) void vq_screen_kernel(
    const float* __restrict__ z, float* __restrict__ ws) {
    __shared__ float lds_w2h[K_CODES];  // -w2/2

    int tid = threadIdx.x;
    int l = tid & 63, wave = tid >> 6;
    int m = l & 15, q = l >> 4;

    {
        float4 wv = ((const float4*)(ws + WS_W2))[tid];
        float4 hv;
        hv.x = -0.5f * wv.x;
        hv.y = -0.5f * wv.y;
        hv.z = -0.5f * wv.z;
        hv.w = -0.5f * wv.w;
        *(float4*)&lds_w2h[tid * 4] = hv;
    }

    int rowbase = blockIdx.x * 128 + wave * 32;
    bf16x8 zhi[2][2], zlo[2][2];
#pragma unroll
    for (int g = 0; g < 2; ++g) {
        const float* zr = z + (size_t)(rowbase + g * 16 + m) * DIM + q * 8;
        cvt_frag(zr, zhi[g][0], zlo[g][0]);
        cvt_frag(zr + 32, zhi[g][1], zlo[g][1]);
    }

    float kv[2], k2[2];
    kv[0] = kv[1] = -3.4e38f;
    k2[0] = k2[1] = -3.4e38f;

    const bf16x8* __restrict__ gh = (const bf16x8*)(ws + WS_WHIP);
    const bf16x8* __restrict__ gl = (const bf16x8*)(ws + WS_WLOP);

    __syncthreads();  // w2h staged; the only barrier in the kernel

    for (int cch = 0; cch < 8; ++cch) {
#pragma unroll 2
        for (int tg = 0; tg < 8; ++tg) {
            int gi = cch * 1024 + tg * 128 + l;
            bf16x8 bh0 = gh[gi];        // codes cbase16, K 0..31 (hi)
            bf16x8 bh1 = gh[gi + 64];   // same codes, K 32..63 (hi)
            bf16x8 bl0 = gl[gi];
            bf16x8 bl1 = gl[gi + 64];
            unsigned cbase = (unsigned)(cch * 128 + tg * 16 + q * 4);
            unsigned ibase = (unsigned)((cch * 8 + tg) * 4);  // 8-bit local idx
            f32x4 cinit = *(const f32x4*)&lds_w2h[cbase];  // -w2/2 for 4 codes
#pragma unroll
            for (int g = 0; g < 2; ++g) {
                f32x4 acc = cinit;
                acc = __builtin_amdgcn_mfma_f32_16x16x32_bf16(bh0, zlo[g][0], acc, 0, 0, 0);
                acc = __builtin_amdgcn_mfma_f32_16x16x32_bf16(bl0, zhi[g][0], acc, 0, 0, 0);
                acc = __builtin_amdgcn_mfma_f32_16x16x32_bf16(bh1, zlo[g][1], acc, 0, 0, 0);
                acc = __builtin_amdgcn_mfma_f32_16x16x32_bf16(bl1, zhi[g][1], acc, 0, 0, 0);
                acc = __builtin_amdgcn_mfma_f32_16x16x32_bf16(bh0, zhi[g][0], acc, 0, 0, 0);
                acc = __builtin_amdgcn_mfma_f32_16x16x32_bf16(bh1, zhi[g][1], acc, 0, 0, 0);
                // pack local idx into low 8 mantissa bits (v_and_or_b32 each)
                float a0 = __uint_as_float((__float_as_uint(acc[0]) & 0xFFFFFF00u) | ibase);
                float a1 = __uint_as_float((__float_as_uint(acc[1]) & 0xFFFFFF00u) | (ibase + 1u));
                float a2 = __uint_as_float((__float_as_uint(acc[2]) & 0xFFFFFF00u) | (ibase + 2u));
                float a3 = __uint_as_float((__float_as_uint(acc[3]) & 0xFFFFFF00u) | (ibase + 3u));
                // top-2 of 4 (tournament), then merge into running top-2
                float m01 = fmaxf(a0, a1), n01 = fminf(a0, a1);
                float m23 = fmaxf(a2, a3), n23 = fminf(a2, a3);
                float top = fmaxf(m01, m23);
                float sec = fmaxf(fmaxf(fminf(m01, m23), n01), n23);  // max3
                k2[g] = fmaxf(fmaxf(k2[g], sec), fminf(kv[g], top));  // max3
                kv[g] = fmaxf(kv[g], top);
            }
        }
    }

    // unpack (masked value, full code), exact take-reduce across the 4 q-lanes
    float mv[2], m2[2];
    int mi[2];
#pragma unroll
    for (int g = 0; g < 2; ++g) {
        unsigned kb = __float_as_uint(kv[g]);
        unsigned i8 = kb & 255u;
        mi[g] = (int)((i8 >> 5) * 128 + ((i8 >> 2) & 7) * 16 + (unsigned)q * 4 + (i8 & 3));
        mv[g] = __uint_as_float(kb & 0xFFFFFF00u);
        m2[g] = __uint_as_float(__float_as_uint(k2[g]) & 0xFFFFFF00u);
    }
#pragma unroll
    for (int o = 16; o < 64; o <<= 1) {
#pragma unroll
        for (int g = 0; g < 2; ++g) {
            float ov = __shfl_xor(mv[g], o, 64);
            float ov2 = __shfl_xor(m2[g], o, 64);
            int oi = __shfl_xor(mi[g], o, 64);
            float nm2 = fmaxf(fmaxf(m2[g], ov2), fminf(mv[g], ov));
            bool take = (ov > mv[g]) || (ov == mv[g] && oi < mi[g]);
            mv[g] = take ? ov : mv[g];
            mi[g] = take ? oi : mi[g];
            m2[g] = nm2;
        }
    }
    if (q == 0) {
#pragma unroll
        for (int g = 0; g < 2; ++g) {
            bool amb = (mv[g] - m2[g]) <= SDELTA;
            ((int*)ws)[WS_MINI + rowbase + g * 16 + m] = mi[g] | (amb ? 0x80000000 : 0);
        }
    }
}

// Per-row: unambiguous -> write idx, z_q_st, loss; ambiguous -> enqueue.
// Wave-cooperative: 16 lanes per row (float4 per lane), 4 rows per step;
// every z load / w load / z_q store is a contiguous, coalesced 1KB/instr.
__global__ __launch_bounds__(256) void vq_gather_kernel(
    const float* __restrict__ z, const float* __restrict__ w,
    float* __restrict__ ws, float* __restrict__ out) {
    __shared__ float lred[4];
    int tid = threadIdx.x;
    int lane = tid & 63, wave = tid >> 6;
    int rsub = lane >> 4;  // 0..3: which of 4 rows this lane serves
    int d4 = lane & 15;    // float4 index within the 64-float row
    int wavebase = blockIdx.x * 256 + wave * 64;

    // prefetch all 16 enc values (independent scalar loads -> MLP)
    int encv[16];
#pragma unroll
    for (int s = 0; s < 16; ++s)
        encv[s] = ((const int*)ws)[WS_MINI + wavebase + s * 4 + rsub];

    float lsum = 0.f;
#pragma unroll
    for (int s = 0; s < 16; ++s) {
        int row = wavebase + s * 4 + rsub;
        int enc = encv[s];
        if (enc >= 0) {
            float4 x = ((const float4*)(z + (size_t)row * DIM))[d4];
            float4 qv = ((const float4*)(w + (size_t)enc * DIM))[d4];
            float4 st;
            st.x = x.x + (qv.x - x.x);
            st.y = x.y + (qv.y - x.y);
            st.z = x.z + (qv.z - x.z);
            st.w = x.w + (qv.w - x.w);
            ((float4*)(out + OUT_ZQ + (size_t)row * DIM))[d4] = st;
            float e0 = x.x - qv.x, e1 = x.y - qv.y, e2 = x.z - qv.z, e3 = x.w - qv.w;
            lsum += e0 * e0;
            lsum += e1 * e1;
            lsum += e2 * e2;
            lsum += e3 * e3;
            if (d4 == 0) out[OUT_IDX + row] = (float)enc;
        } else if (d4 == 0) {
            int pos = atomicAdd((int*)ws + WS_QCOUNT, 1);
            ((int*)ws)[WS_QUEUE + pos] = row;
        }
    }
#pragma unroll
    for (int o = 32; o; o >>= 1) lsum += __shfl_down(lsum, o, 64);
    if (lane == 0) lred[wave] = lsum;
    __syncthreads();
    if (tid == 0) atomicAdd(ws + WS_LOSS, lred[0] + lred[1] + lred[2] + lred[3]);
}

// Exact fp32 argmin for ambiguous rows. Block = 4 rows x 4 waves; each wave
// scans a disjoint 256-code quarter for the SAME 4 rows (w reads broadcast
// across the 4 row-groups in-wave; 16-lane dot reduce via DPP row_ror).
// LDS-combine keeps the exact lowest-index tie-break.
__global__ __launch_bounds__(256) void vq_fixup_kernel(
    const float* __restrict__ z, const float* __restrict__ w,
    float* __restrict__ ws, float* __restrict__ out) {
    const float* __restrict__ w2 = ws + WS_W2;
    __shared__ float sdd[4][4];
    __shared__ int sbi[4][4];
    int count = ((const int*)ws)[WS_QCOUNT];
    int tid = threadIdx.x;
    int lane = tid & 63, wave = tid >> 6;
    int sub = lane >> 4, d4 = lane & 15;
    float lacc = 0.f;
    for (int q0 = blockIdx.x * 4; q0 < count; q0 += gridDim.x * 4) {
        int qi = q0 + sub;
        bool active = qi < count;
        int row = ((const int*)ws)[WS_QUEUE + (active ? qi : 0)];
        float4 zx = ((const float4*)(z + (size_t)row * DIM))[d4];
        float zp = zx.x * zx.x;
        zp = fmaf(zx.y, zx.y, zp);
        zp = fmaf(zx.z, zx.z, zp);
        zp = fmaf(zx.w, zx.w, zp);
        float z2 = red16(zp);
        float best = 3.4e38f;
        int bi = 0;
        int c0 = wave * 256;
#pragma unroll 4
        for (int cc = 0; cc < 256; ++cc) {
            int c = c0 + cc;
            float4 wv4 = ((const float4*)(w + (size_t)c * DIM))[d4];
            float p = zx.x * wv4.x;
            p = fmaf(zx.y, wv4.y, p);
            p = fmaf(zx.z, wv4.z, p);
            p = fmaf(zx.w, wv4.w, p);
            p = red16(p);
            float dd = (z2 - 2.f * p) + w2[c];
            if (dd < best) { best = dd; bi = c; }
        }
        if (d4 == 0) { sdd[wave][sub] = best; sbi[wave][sub] = bi; }
        __syncthreads();
        if (wave == 0 && active) {
            float fb = sdd[0][sub];
            int fbi = sbi[0][sub];
#pragma unroll
            for (int v = 1; v < 4; ++v) {
                float od = sdd[v][sub];
                int oi = sbi[v][sub];
                if (od < fb || (od == fb && oi < fbi)) { fb = od; fbi = oi; }
            }
            float4 qv = ((const float4*)(w + (size_t)fbi * DIM))[d4];
            float4 st;
            st.x = zx.x + (qv.x - zx.x);
            st.y = zx.y + (qv.y - zx.y);
            st.z = zx.z + (qv.z - zx.z);
            st.w = zx.w + (qv.w - zx.w);
            ((float4*)(out + OUT_ZQ + (size_t)row * DIM))[d4] = st;
            float e0 = zx.x - qv.x, e1 = zx.y - qv.y;
            float e2 = zx.z - qv.z, e3 = zx.w - qv.w;
            float ls = e0 * e0 + e1 * e1 + e2 * e2 + e3 * e3;
            ls = red16(ls);
            if (d4 == 0) {
                out[OUT_IDX + row] = (float)fbi;
                lacc += ls;
            }
        }
        __syncthreads();
    }
    lacc += __shfl_xor(lacc, 16, 64);
    lacc += __shfl_xor(lacc, 32, 64);
    if (tid == 0 && lacc != 0.f) atomicAdd(ws + WS_LOSS, lacc);
}

// Segment-sum: r9's proven ballot-compact gather structure (125us; global
// atomics r12 = 338us write-through disaster, stream+LDS r10/r11 = 180us),
// with the ONE untested axis changed: BLOCK COUNT. 16 code-splits x 32
// row-slices = 512 blocks (r0/r9 both had 256 and identical 125us despite
// 4x wave difference -- wall is either per-block serialization or chip-wide
// random-line throughput; this disambiguates). LDS 32.3KB -> 2 blocks/CU
// co-resident. Partials 512x4096 / counts 512x64 exactly fill EPART/CPART.
__global__ __launch_bounds__(1024) void vq_embed_kernel(
    const float* __restrict__ z, const float* __restrict__ idx_f,
    float* __restrict__ ws) {
    __shared__ float eacc[64 * DIM];   // 16 KB
    __shared__ float ecnt[64];
    __shared__ int lists[16][256];     // 16 KB
    int b = blockIdx.x;
    int cs = b & 15, rs = b >> 4;
    float lo = (float)(cs * 64), hi = lo + 64.f;
    int tid = threadIdx.x;
    int wave = tid >> 6, lane = tid & 63;

#pragma unroll
    for (int j = 0; j < 4; ++j) eacc[j * 1024 + tid] = 0.f;
    if (tid < 64) ecnt[tid] = 0.f;
    __syncthreads();

    const float4* idx4 = (const float4*)idx_f;
    unsigned long long lanebits = (1ull << lane) - 1ull;
    for (int it = 0; it < 2; ++it) {
        int base = rs * 8192 + wave * 512 + it * 256;
        float4 f = idx4[(base >> 2) + lane];
        int cnt = 0;
#pragma unroll
        for (int c = 0; c < 4; ++c) {
            float fv = (c == 0) ? f.x : (c == 1) ? f.y : (c == 2) ? f.z : f.w;
            bool match = (fv >= lo && fv < hi);
            unsigned long long mmask = __ballot(match);
            if (match) {
                int pos = cnt + __popcll(mmask & lanebits);
                int row = base + 4 * lane + c;
                int local = (int)fv - cs * 64;
                lists[wave][pos] = (row << 6) | local;
                atomicAdd(&ecnt[local], 1.f);
            }
            cnt += __popcll(mmask);
        }
        int j = 0;
        for (; j + 4 <= cnt; j += 4) {
            int e0 = lists[wave][j], e1 = lists[wave][j + 1];
            int e2 = lists[wave][j + 2], e3 = lists[wave][j + 3];
            float v0 = z[(size_t)(e0 >> 6) * DIM + lane];
            float v1 = z[(size_t)(e1 >> 6) * DIM + lane];
            float v2 = z[(size_t)(e2 >> 6) * DIM + lane];
            float v3 = z[(size_t)(e3 >> 6) * DIM + lane];
            atomicAdd(&eacc[(e0 & 63) * DIM + lane], v0);
            atomicAdd(&eacc[(e1 & 63) * DIM + lane], v1);
            atomicAdd(&eacc[(e2 & 63) * DIM + lane], v2);
            atomicAdd(&eacc[(e3 & 63) * DIM + lane], v3);
        }
        for (; j < cnt; ++j) {
            int e = lists[wave][j];
            float v = z[(size_t)(e >> 6) * DIM + lane];
            atomicAdd(&eacc[(e & 63) * DIM + lane], v);
        }
    }
    __syncthreads();
#pragma unroll
    for (int j = 0; j < 4; ++j)
        ws[WS_EPART + (size_t)b * 4096 + j * 1024 + tid] = eacc[j * 1024 + tid];
    if (tid < 64) ws[WS_CPART + b * 64 + tid] = ecnt[tid];
}

__global__ __launch_bounds__(1024) void vq_finalize1_kernel(
    const float* __restrict__ ema_cs, float* __restrict__ ws,
    float* __restrict__ out) {
    int k = threadIdx.x;
    int cs = k >> 6, local = k & 63;
    float c = 0.f;
#pragma unroll
    for (int rs = 0; rs < 32; ++rs) c += ws[WS_CPART + (rs * 16 + cs) * 64 + local];
    float nc = 0.99f * ema_cs[k] + 0.01f * c;
    out[OUT_NEWCS + k] = nc;

    float s = nc;
#pragma unroll
    for (int o = 32; o; o >>= 1) s += __shfl_down(s, o, 64);
    __shared__ float red[16];
    __shared__ float n_sh;
    if ((k & 63) == 0) red[k >> 6] = s;
    __syncthreads();
    if (k == 0) {
        float n = 0.f;
#pragma unroll
        for (int i = 0; i < 16; ++i) n += red[i];
        n_sh = n;
        out[OUT_LOSS] = 0.25f * (ws[WS_LOSS] / 16777216.0f);
    }
    __syncthreads();
    float n = n_sh;
    ws[WS_SMOOTH + k] = (nc + 1e-5f) / (n + 0.01024f) * n;
}

__global__ __launch_bounds__(256) void vq_finalize2_kernel(
    const float* __restrict__ ema_es, const float* __restrict__ ws,
    float* __restrict__ out) {
    int i = blockIdx.x * 256 + threadIdx.x;  // 65536 elems = code*64+dim
    int code = i >> 6, dim = i & 63;
    int cs = code >> 6, local = code & 63;
    float e = 0.f;
#pragma unroll
    for (int rs = 0; rs < 32; ++rs)
        e += ws[WS_EPART + (size_t)(rs * 16 + cs) * 4096 + local * DIM + dim];
    float es = 0.99f * ema_es[i] + 0.01f * e;
    out[OUT_NEWES + i] = es;
    out[OUT_NEWW + i] = es / ws[WS_SMOOTH + code];
}

extern "C" void kernel_launch(void* const* d_in, const int* in_sizes, int n_in,
                              void* d_out, int out_size, void* d_ws, size_t ws_size,
                              hipStream_t stream) {
    const float* z = (const float*)d_in[0];
    const float* weight = (const float*)d_in[1];
    const float* ema_cs = (const float*)d_in[2];
    const float* ema_es = (const float*)d_in[3];
    float* out = (float*)d_out;
    float* ws = (float*)d_ws;

    hipMemsetAsync(ws, 0, 64, stream);  // loss + queue counter
    vq_prep<<<36, 256, 0, stream>>>(weight, ws);
    vq_screen_kernel<<<B_ROWS / 128, 256, 0, stream>>>(z, ws);
    vq_gather_kernel<<<B_ROWS / 256, 256, 0, stream>>>(z, weight, ws, out);
    vq_fixup_kernel<<<512, 256, 0, stream>>>(z, weight, ws, out);
    vq_embed_kernel<<<512, 1024, 0, stream>>>(z, out + OUT_IDX, ws);
    vq_finalize1_kernel<<<1, 1024, 0, stream>>>(ema_cs, ws, out);
    vq_finalize2_kernel<<<256, 256, 0, stream>>>(ema_es, ws, out);
}

// Round 14
// 390.735 us; speedup vs baseline: 1.5499x; 1.0826x over previous
//
#include <hip/hip_runtime.h>

typedef __attribute__((ext_vector_type(8))) short bf16x8;
typedef __attribute__((ext_vector_type(4))) float f32x4;

#define B_ROWS 262144
#define K_CODES 1024
#define DIM 64
// screen ambiguity threshold in s-units (s = dot - w2/2; d-gap = 2*s-gap).
// 8-bit packed-key noise (<=0.008 pairwise at |s|<=128) + bf16-split dot
// error (<=0.004 pairwise) -> 0.012; SDELTA=0.015 with margin.
#define SDELTA 0.015f

// output layout (floats)
#define OUT_ZQ 0
#define OUT_IDX 16777216
#define OUT_LOSS 17039360
#define OUT_NEWCS 17039361
#define OUT_NEWES 17040385
#define OUT_NEWW 17105921

// ws layout (float indices); ~10.9 MB total
#define WS_LOSS   0
#define WS_QCOUNT 1
#define WS_W2     16
#define WS_SMOOTH 1040
#define WS_WHIP   2064      // permuted hi codebook: 8192 granules x 16B
#define WS_WLOP   34832     // permuted lo codebook
#define WS_CPART  67600     // 256 blocks * 128 codes
#define WS_EPART  100368    // 256 blocks * 128 codes * 64 dims
#define WS_MINI   2197520   // int[262144]; bit31 = ambiguous
#define WS_QUEUE  2459664   // int[262144]

static __device__ __forceinline__ unsigned short f2bf(float x) {
    unsigned u = __float_as_uint(x);
    return (unsigned short)((u + 0x7fffu + ((u >> 16) & 1u)) >> 16);  // RN-even
}
static __device__ __forceinline__ float bf2f(unsigned short u) {
    return __uint_as_float(((unsigned)u) << 16);
}

// sum across each 16-lane group via DPP row_ror (VALU pipe only -- r8 lesson:
// __shfl_xor chains hit the LDS pipe, ~300cyc/code serial at low occupancy)
static __device__ __forceinline__ float red16(float x) {
    int v;
    v = __builtin_amdgcn_update_dpp(0, __float_as_int(x), 0x128, 0xF, 0xF, true);
    x += __int_as_float(v);
    v = __builtin_amdgcn_update_dpp(0, __float_as_int(x), 0x124, 0xF, 0xF, true);
    x += __int_as_float(v);
    v = __builtin_amdgcn_update_dpp(0, __float_as_int(x), 0x122, 0xF, 0xF, true);
    x += __int_as_float(v);
    v = __builtin_amdgcn_update_dpp(0, __float_as_int(x), 0x121, 0xF, 0xF, true);
    x += __int_as_float(v);
    return x;
}

static __device__ __forceinline__ void cvt_frag(const float* zrow, bf16x8& hi, bf16x8& lo) {
    float4 f0 = *(const float4*)zrow;
    float4 f1 = *(const float4*)(zrow + 4);
    float tf[8] = {f0.x, f0.y, f0.z, f0.w, f1.x, f1.y, f1.z, f1.w};
#pragma unroll
    for (int j = 0; j < 8; ++j) {
        unsigned short h = f2bf(tf[j]);
        hi[j] = (short)h;
        lo[j] = (short)f2bf(tf[j] - bf2f(h));
    }
}

// blocks 0..3: w2 row norms. blocks 4..35: permute codebook into MFMA-granule
// order: chunk c (128 codes), position p: granule = (code c*128+(p>>7)*16+(p&15),
// octet ((p>>6)&1)*4 + ((p>>4)&3)). Lane l reads granule base+l -> 16 codes x
// one K=32 half; base+l+64 -> same codes, other K half.
__global__ __launch_bounds__(256) void vq_prep(const float* __restrict__ w,
                                               float* __restrict__ ws) {
    int b = blockIdx.x, tid = threadIdx.x;
    if (b < 4) {
        int k = b * 256 + tid;
        const float4* w4 = (const float4*)(w + (size_t)k * DIM);
        float s = 0.f;
#pragma unroll
        for (int j = 0; j < 16; ++j) {
            float4 v = w4[j];
            s += v.x * v.x + v.y * v.y + v.z * v.z + v.w * v.w;
        }
        ws[WS_W2 + k] = s;
    } else {
        int i = (b - 4) * 256 + tid;  // granule index 0..8191
        int p = i & 1023, c = i >> 10;
        int code = c * 128 + ((p >> 7) << 4) + (p & 15);
        int octet = ((p >> 6) & 1) * 4 + ((p >> 4) & 3);
        const float* src = w + (size_t)code * DIM + octet * 8;
        float4 f0 = *(const float4*)src;
        float4 f1 = *(const float4*)(src + 4);
        float tf[8] = {f0.x, f0.y, f0.z, f0.w, f1.x, f1.y, f1.z, f1.w};
        bf16x8 hv, lv;
#pragma unroll
        for (int j = 0; j < 8; ++j) {
            unsigned short hb = f2bf(tf[j]);
            hv[j] = (short)hb;
            lv[j] = (short)f2bf(tf[j] - bf2f(hb));
        }
        ((bf16x8*)(ws + WS_WHIP))[i] = hv;
        ((bf16x8*)(ws + WS_WLOP))[i] = lv;
    }
}

// MFMA 16x16x32 screening, barrier-free, operand-swapped (A=codebook, B=z),
// g=4 ROW-GROUPS PER WAVE (64 rows). Rationale: each wave streams the ENTIRE
// permuted codebook from L2 (256 KB hi+lo) regardless of g -- at g=2 that is
// 8192 waves x 256 KB = 2.1 GB of L2 reads, the suspected ~105us wall.
// g=4 halves wave count -> halves codebook L2 traffic. The r3/r4 spill
// trap does not apply: packed-key state is slim (z-frags 64 + kv/k2 8 +
// B-in-flight 16 + addr ~= 110 regs < the waves_per_eu(3,4) 170 budget;
// r5's g=2 compiled to 60). Each lane's 4 acc values are 4 codes of ONE
// z-row; w2/2 pre-folded into the MFMA C-init. 8-bit packed keys: lane-local
// candidate index in the low 8 mantissa bits; full code recovered in the
// epilogue; corrupted orderings have gap <= SDELTA -> exact fixup path.
__global__ __launch_bounds__(256)
__attribute__((amdgpu_waves_per_eu(3, 4))) void vq_screen_kernel(
    const float* __restrict__ z, float* __restrict__ ws) {
    __shared__ float lds_w2h[K_CODES];  // -w2/2

    int tid = threadIdx.x;
    int l = tid & 63, wave = tid >> 6;
    int m = l & 15, q = l >> 4;

    {
        float4 wv = ((const float4*)(ws + WS_W2))[tid];
        float4 hv;
        hv.x = -0.5f * wv.x;
        hv.y = -0.5f * wv.y;
        hv.z = -0.5f * wv.z;
        hv.w = -0.5f * wv.w;
        *(float4*)&lds_w2h[tid * 4] = hv;
    }

    int rowbase = blockIdx.x * 256 + wave * 64;
    bf16x8 zhi[4][2], zlo[4][2];
#pragma unroll
    for (int g = 0; g < 4; ++g) {
        const float* zr = z + (size_t)(rowbase + g * 16 + m) * DIM + q * 8;
        cvt_frag(zr, zhi[g][0], zlo[g][0]);
        cvt_frag(zr + 32, zhi[g][1], zlo[g][1]);
    }

    float kv[4], k2[4];
#pragma unroll
    for (int g = 0; g < 4; ++g) { kv[g] = -3.4e38f; k2[g] = -3.4e38f; }

    const bf16x8* __restrict__ gh = (const bf16x8*)(ws + WS_WHIP);
    const bf16x8* __restrict__ gl = (const bf16x8*)(ws + WS_WLOP);

    __syncthreads();  // w2h staged; the only barrier in the kernel

    for (int cch = 0; cch < 8; ++cch) {
#pragma unroll 2
        for (int tg = 0; tg < 8; ++tg) {
            int gi = cch * 1024 + tg * 128 + l;
            bf16x8 bh0 = gh[gi];        // codes cbase16, K 0..31 (hi)
            bf16x8 bh1 = gh[gi + 64];   // same codes, K 32..63 (hi)
            bf16x8 bl0 = gl[gi];
            bf16x8 bl1 = gl[gi + 64];
            unsigned cbase = (unsigned)(cch * 128 + tg * 16 + q * 4);
            unsigned ibase = (unsigned)((cch * 8 + tg) * 4);  // 8-bit local idx
            f32x4 cinit = *(const f32x4*)&lds_w2h[cbase];  // -w2/2 for 4 codes
#pragma unroll
            for (int g = 0; g < 4; ++g) {
                f32x4 acc = cinit;
                acc = __builtin_amdgcn_mfma_f32_16x16x32_bf16(bh0, zlo[g][0], acc, 0, 0, 0);
                acc = __builtin_amdgcn_mfma_f32_16x16x32_bf16(bl0, zhi[g][0], acc, 0, 0, 0);
                acc = __builtin_amdgcn_mfma_f32_16x16x32_bf16(bh1, zlo[g][1], acc, 0, 0, 0);
                acc = __builtin_amdgcn_mfma_f32_16x16x32_bf16(bl1, zhi[g][1], acc, 0, 0, 0);
                acc = __builtin_amdgcn_mfma_f32_16x16x32_bf16(bh0, zhi[g][0], acc, 0, 0, 0);
                acc = __builtin_amdgcn_mfma_f32_16x16x32_bf16(bh1, zhi[g][1], acc, 0, 0, 0);
                // pack local idx into low 8 mantissa bits (v_and_or_b32 each)
                float a0 = __uint_as_float((__float_as_uint(acc[0]) & 0xFFFFFF00u) | ibase);
                float a1 = __uint_as_float((__float_as_uint(acc[1]) & 0xFFFFFF00u) | (ibase + 1u));
                float a2 = __uint_as_float((__float_as_uint(acc[2]) & 0xFFFFFF00u) | (ibase + 2u));
                float a3 = __uint_as_float((__float_as_uint(acc[3]) & 0xFFFFFF00u) | (ibase + 3u));
                // top-2 of 4 (tournament), then merge into running top-2
                float m01 = fmaxf(a0, a1), n01 = fminf(a0, a1);
                float m23 = fmaxf(a2, a3), n23 = fminf(a2, a3);
                float top = fmaxf(m01, m23);
                float sec = fmaxf(fmaxf(fminf(m01, m23), n01), n23);  // max3
                k2[g] = fmaxf(fmaxf(k2[g], sec), fminf(kv[g], top));  // max3
                kv[g] = fmaxf(kv[g], top);
            }
        }
    }

    // unpack (masked value, full code), exact take-reduce across the 4 q-lanes
    float mv[4], m2[4];
    int mi[4];
#pragma unroll
    for (int g = 0; g < 4; ++g) {
        unsigned kb = __float_as_uint(kv[g]);
        unsigned i8 = kb & 255u;
        mi[g] = (int)((i8 >> 5) * 128 + ((i8 >> 2) & 7) * 16 + (unsigned)q * 4 + (i8 & 3));
        mv[g] = __uint_as_float(kb & 0xFFFFFF00u);
        m2[g] = __uint_as_float(__float_as_uint(k2[g]) & 0xFFFFFF00u);
    }
#pragma unroll
    for (int o = 16; o < 64; o <<= 1) {
#pragma unroll
        for (int g = 0; g < 4; ++g) {
            float ov = __shfl_xor(mv[g], o, 64);
            float ov2 = __shfl_xor(m2[g], o, 64);
            int oi = __shfl_xor(mi[g], o, 64);
            float nm2 = fmaxf(fmaxf(m2[g], ov2), fminf(mv[g], ov));
            bool take = (ov > mv[g]) || (ov == mv[g] && oi < mi[g]);
            mv[g] = take ? ov : mv[g];
            mi[g] = take ? oi : mi[g];
            m2[g] = nm2;
        }
    }
    if (q == 0) {
#pragma unroll
        for (int g = 0; g < 4; ++g) {
            bool amb = (mv[g] - m2[g]) <= SDELTA;
            ((int*)ws)[WS_MINI + rowbase + g * 16 + m] = mi[g] | (amb ? 0x80000000 : 0);
        }
    }
}

// Per-row: unambiguous -> write idx, z_q_st, loss; ambiguous -> enqueue.
// Wave-cooperative: 16 lanes per row (float4 per lane), 4 rows per step;
// every z load / w load / z_q store is a contiguous, coalesced 1KB/instr.
__global__ __launch_bounds__(256) void vq_gather_kernel(
    const float* __restrict__ z, const float* __restrict__ w,
    float* __restrict__ ws, float* __restrict__ out) {
    __shared__ float lred[4];
    int tid = threadIdx.x;
    int lane = tid & 63, wave = tid >> 6;
    int rsub = lane >> 4;  // 0..3: which of 4 rows this lane serves
    int d4 = lane & 15;    // float4 index within the 64-float row
    int wavebase = blockIdx.x * 256 + wave * 64;

    // prefetch all 16 enc values (independent scalar loads -> MLP)
    int encv[16];
#pragma unroll
    for (int s = 0; s < 16; ++s)
        encv[s] = ((const int*)ws)[WS_MINI + wavebase + s * 4 + rsub];

    float lsum = 0.f;
#pragma unroll
    for (int s = 0; s < 16; ++s) {
        int row = wavebase + s * 4 + rsub;
        int enc = encv[s];
        if (enc >= 0) {
            float4 x = ((const float4*)(z + (size_t)row * DIM))[d4];
            float4 qv = ((const float4*)(w + (size_t)enc * DIM))[d4];
            float4 st;
            st.x = x.x + (qv.x - x.x);
            st.y = x.y + (qv.y - x.y);
            st.z = x.z + (qv.z - x.z);
            st.w = x.w + (qv.w - x.w);
            ((float4*)(out + OUT_ZQ + (size_t)row * DIM))[d4] = st;
            float e0 = x.x - qv.x, e1 = x.y - qv.y, e2 = x.z - qv.z, e3 = x.w - qv.w;
            lsum += e0 * e0;
            lsum += e1 * e1;
            lsum += e2 * e2;
            lsum += e3 * e3;
            if (d4 == 0) out[OUT_IDX + row] = (float)enc;
        } else if (d4 == 0) {
            int pos = atomicAdd((int*)ws + WS_QCOUNT, 1);
            ((int*)ws)[WS_QUEUE + pos] = row;
        }
    }
#pragma unroll
    for (int o = 32; o; o >>= 1) lsum += __shfl_down(lsum, o, 64);
    if (lane == 0) lred[wave] = lsum;
    __syncthreads();
    if (tid == 0) atomicAdd(ws + WS_LOSS, lred[0] + lred[1] + lred[2] + lred[3]);
}

// Exact fp32 argmin for ambiguous rows. Block = 4 rows x 4 waves; each wave
// scans a disjoint 256-code quarter for the SAME 4 rows (w reads broadcast
// across the 4 row-groups in-wave; 16-lane dot reduce via DPP row_ror).
// LDS-combine keeps the exact lowest-index tie-break.
__global__ __launch_bounds__(256) void vq_fixup_kernel(
    const float* __restrict__ z, const float* __restrict__ w,
    float* __restrict__ ws, float* __restrict__ out) {
    const float* __restrict__ w2 = ws + WS_W2;
    __shared__ float sdd[4][4];
    __shared__ int sbi[4][4];
    int count = ((const int*)ws)[WS_QCOUNT];
    int tid = threadIdx.x;
    int lane = tid & 63, wave = tid >> 6;
    int sub = lane >> 4, d4 = lane & 15;
    float lacc = 0.f;
    for (int q0 = blockIdx.x * 4; q0 < count; q0 += gridDim.x * 4) {
        int qi = q0 + sub;
        bool active = qi < count;
        int row = ((const int*)ws)[WS_QUEUE + (active ? qi : 0)];
        float4 zx = ((const float4*)(z + (size_t)row * DIM))[d4];
        float zp = zx.x * zx.x;
        zp = fmaf(zx.y, zx.y, zp);
        zp = fmaf(zx.z, zx.z, zp);
        zp = fmaf(zx.w, zx.w, zp);
        float z2 = red16(zp);
        float best = 3.4e38f;
        int bi = 0;
        int c0 = wave * 256;
#pragma unroll 4
        for (int cc = 0; cc < 256; ++cc) {
            int c = c0 + cc;
            float4 wv4 = ((const float4*)(w + (size_t)c * DIM))[d4];
            float p = zx.x * wv4.x;
            p = fmaf(zx.y, wv4.y, p);
            p = fmaf(zx.z, wv4.z, p);
            p = fmaf(zx.w, wv4.w, p);
            p = red16(p);
            float dd = (z2 - 2.f * p) + w2[c];
            if (dd < best) { best = dd; bi = c; }
        }
        if (d4 == 0) { sdd[wave][sub] = best; sbi[wave][sub] = bi; }
        __syncthreads();
        if (wave == 0 && active) {
            float fb = sdd[0][sub];
            int fbi = sbi[0][sub];
#pragma unroll
            for (int v = 1; v < 4; ++v) {
                float od = sdd[v][sub];
                int oi = sbi[v][sub];
                if (od < fb || (od == fb && oi < fbi)) { fb = od; fbi = oi; }
            }
            float4 qv = ((const float4*)(w + (size_t)fbi * DIM))[d4];
            float4 st;
            st.x = zx.x + (qv.x - zx.x);
            st.y = zx.y + (qv.y - zx.y);
            st.z = zx.z + (qv.z - zx.z);
            st.w = zx.w + (qv.w - zx.w);
            ((float4*)(out + OUT_ZQ + (size_t)row * DIM))[d4] = st;
            float e0 = zx.x - qv.x, e1 = zx.y - qv.y;
            float e2 = zx.z - qv.z, e3 = zx.w - qv.w;
            float ls = e0 * e0 + e1 * e1 + e2 * e2 + e3 * e3;
            ls = red16(ls);
            if (d4 == 0) {
                out[OUT_IDX + row] = (float)fbi;
                lacc += ls;
            }
        }
        __syncthreads();
    }
    lacc += __shfl_xor(lacc, 16, 64);
    lacc += __shfl_xor(lacc, 32, 64);
    if (tid == 0 && lacc != 0.f) atomicAdd(ws + WS_LOSS, lacc);
}

// Segment-sum: r9's proven structure, reverted verbatim (125us floor).
// 8 code-splits x 32 row-slices = 256 blocks; ballot-compact matched rows
// into an LDS list, then gather 4 rows per step (4x MLP); LDS accumulate.
// r13 falsified the block-count axis (512 blocks = 149us); r10-r12
// falsified streaming-LDS (180) and global atomics (338). This is the
// empirical floor of the embed class.
__global__ __launch_bounds__(1024) void vq_embed_kernel(
    const float* __restrict__ z, const float* __restrict__ idx_f,
    float* __restrict__ ws) {
    __shared__ float eacc[128 * DIM];  // 32 KB
    __shared__ float ecnt[128];
    __shared__ int lists[16][256];     // 16 KB
    int b = blockIdx.x;
    int cs = b & 7, rs = b >> 3;
    float lo = (float)(cs * 128), hi = lo + 128.f;
    int tid = threadIdx.x;
    int wave = tid >> 6, lane = tid & 63;

#pragma unroll
    for (int j = 0; j < 8; ++j) eacc[j * 1024 + tid] = 0.f;
    if (tid < 128) ecnt[tid] = 0.f;
    __syncthreads();

    const float4* idx4 = (const float4*)idx_f;
    unsigned long long lanebits = (1ull << lane) - 1ull;
    for (int it = 0; it < 2; ++it) {
        int base = rs * 8192 + wave * 512 + it * 256;
        float4 f = idx4[(base >> 2) + lane];
        int cnt = 0;
#pragma unroll
        for (int c = 0; c < 4; ++c) {
            float fv = (c == 0) ? f.x : (c == 1) ? f.y : (c == 2) ? f.z : f.w;
            bool match = (fv >= lo && fv < hi);
            unsigned long long mmask = __ballot(match);
            if (match) {
                int pos = cnt + __popcll(mmask & lanebits);
                int row = base + 4 * lane + c;
                int local = (int)fv - cs * 128;
                lists[wave][pos] = (row << 7) | local;
                atomicAdd(&ecnt[local], 1.f);
            }
            cnt += __popcll(mmask);
        }
        int j = 0;
        for (; j + 4 <= cnt; j += 4) {
            int e0 = lists[wave][j], e1 = lists[wave][j + 1];
            int e2 = lists[wave][j + 2], e3 = lists[wave][j + 3];
            float v0 = z[(size_t)(e0 >> 7) * DIM + lane];
            float v1 = z[(size_t)(e1 >> 7) * DIM + lane];
            float v2 = z[(size_t)(e2 >> 7) * DIM + lane];
            float v3 = z[(size_t)(e3 >> 7) * DIM + lane];
            atomicAdd(&eacc[(e0 & 127) * DIM + lane], v0);
            atomicAdd(&eacc[(e1 & 127) * DIM + lane], v1);
            atomicAdd(&eacc[(e2 & 127) * DIM + lane], v2);
            atomicAdd(&eacc[(e3 & 127) * DIM + lane], v3);
        }
        for (; j < cnt; ++j) {
            int e = lists[wave][j];
            float v = z[(size_t)(e >> 7) * DIM + lane];
            atomicAdd(&eacc[(e & 127) * DIM + lane], v);
        }
    }
    __syncthreads();
#pragma unroll
    for (int j = 0; j < 8; ++j)
        ws[WS_EPART + (size_t)b * 8192 + j * 1024 + tid] = eacc[j * 1024 + tid];
    if (tid < 128) ws[WS_CPART + b * 128 + tid] = ecnt[tid];
}

__global__ __launch_bounds__(1024) void vq_finalize1_kernel(
    const float* __restrict__ ema_cs, float* __restrict__ ws,
    float* __restrict__ out) {
    int k = threadIdx.x;
    int cs = k >> 7, local = k & 127;
    float c = 0.f;
#pragma unroll
    for (int rs = 0; rs < 32; ++rs) c += ws[WS_CPART + (rs * 8 + cs) * 128 + local];
    float nc = 0.99f * ema_cs[k] + 0.01f * c;
    out[OUT_NEWCS + k] = nc;

    float s = nc;
#pragma unroll
    for (int o = 32; o; o >>= 1) s += __shfl_down(s, o, 64);
    __shared__ float red[16];
    __shared__ float n_sh;
    if ((k & 63) == 0) red[k >> 6] = s;
    __syncthreads();
    if (k == 0) {
        float n = 0.f;
#pragma unroll
        for (int i = 0; i < 16; ++i) n += red[i];
        n_sh = n;
        out[OUT_LOSS] = 0.25f * (ws[WS_LOSS] / 16777216.0f);
    }
    __syncthreads();
    float n = n_sh;
    ws[WS_SMOOTH + k] = (nc + 1e-5f) / (n + 0.01024f) * n;
}

__global__ __launch_bounds__(256) void vq_finalize2_kernel(
    const float* __restrict__ ema_es, const float* __restrict__ ws,
    float* __restrict__ out) {
    int i = blockIdx.x * 256 + threadIdx.x;  // 65536 elems = code*64+dim
    int code = i >> 6, dim = i & 63;
    int cs = code >> 7, local = code & 127;
    float e = 0.f;
#pragma unroll
    for (int rs = 0; rs < 32; ++rs)
        e += ws[WS_EPART + (size_t)(rs * 8 + cs) * 8192 + local * DIM + dim];
    float es = 0.99f * ema_es[i] + 0.01f * e;
    out[OUT_NEWES + i] = es;
    out[OUT_NEWW + i] = es / ws[WS_SMOOTH + code];
}

extern "C" void kernel_launch(void* const* d_in, const int* in_sizes, int n_in,
                              void* d_out, int out_size, void* d_ws, size_t ws_size,
                              hipStream_t stream) {
    const float* z = (const float*)d_in[0];
    const float* weight = (const float*)d_in[1];
    const float* ema_cs = (const float*)d_in[2];
    const float* ema_es = (const float*)d_in[3];
    float* out = (float*)d_out;
    float* ws = (float*)d_ws;

    hipMemsetAsync(ws, 0, 64, stream);  // loss + queue counter
    vq_prep<<<36, 256, 0, stream>>>(weight, ws);
    vq_screen_kernel<<<B_ROWS / 256, 256, 0, stream>>>(z, ws);
    vq_gather_kernel<<<B_ROWS / 256, 256, 0, stream>>>(z, weight, ws, out);
    vq_fixup_kernel<<<512, 256, 0, stream>>>(z, weight, ws, out);
    vq_embed_kernel<<<256, 1024, 0, stream>>>(z, out + OUT_IDX, ws);
    vq_finalize1_kernel<<<1, 1024, 0, stream>>>(ema_cs, ws, out);
    vq_finalize2_kernel<<<256, 256, 0, stream>>>(ema_es, ws, out);
}